// Round 6
// baseline (191.260 us; speedup 1.0000x reference)
//
#include <hip/hip_runtime.h>
#include <hip/hip_bf16.h>
#include <stdint.h>

// Problem sizes (compile-time)
static constexpr int BATCH = 32768;
static constexpr int DIN   = 512;
static constexpr int DHID  = 1024;
static constexpr int DOUT  = 2048;

typedef __bf16 bf16x8 __attribute__((ext_vector_type(8)));
typedef float  f32x4  __attribute__((ext_vector_type(4)));

// fp32 -> bf16 round-to-nearest-even
__device__ __forceinline__ unsigned short f2bf(float f) {
    unsigned int u = __float_as_uint(f);
    u += 0x7FFFu + ((u >> 16) & 1u);
    return (unsigned short)(u >> 16);
}

// async global->LDS, 16B per lane. LDS dest = WAVE-uniform base + 16*(lane&63).
__device__ __forceinline__ void gload_lds16(const void* g, void* l) {
    __builtin_amdgcn_global_load_lds((__attribute__((address_space(1))) void*)g,
                                     (__attribute__((address_space(3))) void*)l,
                                     16, 0, 0);
}

// ===========================================================================
// scores = x @ W^T + b' (algebraic fusion; absmax 0.03125 measured)
// r20 = r19 + REGISTER FRAG DOUBLE-BUFFER. r19's measured phase = 1356 cyc
// = 770 (LDS reads) + 620 (MFMA) SERIAL per wave: each phase's MFMA consumed
// that phase's reads, so the LDS and MFMA pipes alternated. Now phase s
// issues ds_reads for slot s into frag set (s&1) and MFMAs frag set (s-1)&1
// (already resident). Reads are serviced DURING the MFMA burst; VMC(6)+
// LGKM0 at phase end preserve r19's exact hazard ledger:
//   WAR: LGKM0 before BAR drains all reads of buffer (s-1)&3 before any
//        wave's phase-s stage overwrites it (stage target (s+3)&3=(s-1)&3).
//   RAW: slot staged at s-3, VMC(6)-forced at s-1, published BAR(s-1),
//        frag-read at s. Unchanged.
//   MM operands: regs guarded by PREV phase's LGKM0+BAR; sched_barrier(0)
//        after each BAR pins against cross-region hoist (rule #18).
// Floor: max(LDS ~770-980, MFMA 620) instead of sum.
// ===========================================================================

// ---------------------------------------------------------------------------
// prep: one dispatch, region-decoded by blockIdx.x.
// r20: x region now 4 float4/thread (grid 18944 -> 6656, less dispatch ramp).
// ---------------------------------------------------------------------------
__global__ __launch_bounds__(256) void prep_kernel(
    const float* __restrict__ w1, const float4* __restrict__ w2f,
    const float4* __restrict__ xf, const float* __restrict__ b1,
    const float* __restrict__ b2,
    unsigned short* __restrict__ w1t, ushort4* __restrict__ w2b,
    ushort4* __restrict__ xb, float* __restrict__ bp) {
    const int blk = blockIdx.x;
    const int t   = threadIdx.x;
    if (blk < 512) {
        __shared__ float tile[32][33];
        const int tileI = blk & 15;
        const int tileH = blk >> 4;
        const int iBase = tileI * 32, hBase = tileH * 32;
        const int col = t & 31, rowq = t >> 5;
#pragma unroll
        for (int p = 0; p < 4; ++p) {
            const int row = p * 8 + rowq;
            tile[row][col] = w1[(size_t)(hBase + row) * DIN + iBase + col];
        }
        __syncthreads();
#pragma unroll
        for (int p = 0; p < 4; ++p) {
            const int row = p * 8 + rowq;
            w1t[(size_t)(iBase + row) * DHID + hBase + col] = f2bf(tile[col][row]);
        }
    } else if (blk < 2560) {
        __shared__ float wsum[4];
        const int o = blk - 512;
        const size_t g = (size_t)o * 256 + t;
        float4 v = w2f[g];
        ushort4 ob;
        ob.x = f2bf(v.x); ob.y = f2bf(v.y); ob.z = f2bf(v.z); ob.w = f2bf(v.w);
        w2b[g] = ob;
        float4 bv = ((const float4*)b1)[t];
        float s = v.x * bv.x + v.y * bv.y + v.z * bv.z + v.w * bv.w;
#pragma unroll
        for (int off = 1; off < 64; off <<= 1) s += __shfl_xor(s, off);
        if ((t & 63) == 0) wsum[t >> 6] = s;
        __syncthreads();
        if (t == 0) bp[o] = wsum[0] + wsum[1] + wsum[2] + wsum[3] + b2[o];
    } else {
        // 4096 blocks x 256 thr x 4 float4 = 4194304 float4 groups
        const size_t base = (size_t)(blk - 2560) * 1024 + t;
#pragma unroll
        for (int i = 0; i < 4; ++i) {
            float4 v = xf[base + i * 256];
            ushort4 o;
            o.x = f2bf(v.x); o.y = f2bf(v.y); o.z = f2bf(v.z); o.w = f2bf(v.w);
            xb[base + i * 256] = o;
        }
    }
}

// ---------------------------------------------------------------------------
// gemmW: W[o,i] = sum_h w2b[o,h] * w1t[i,h]. (unchanged)
// ---------------------------------------------------------------------------
__global__ __launch_bounds__(256) void gemmW_kernel(
    const unsigned short* __restrict__ A,
    const unsigned short* __restrict__ Bw,
    unsigned short* __restrict__ W) {
    constexpr int K = DHID;
    __shared__ __align__(16) unsigned short sA[64 * 128];
    __shared__ __align__(16) unsigned short sB[64 * 128];

    const int tid  = threadIdx.x;
    const int lane = tid & 63;
    const int wid  = tid >> 6;
    const int wr = wid >> 1, wc = wid & 1;
    const int r = lane & 15, q = lane >> 4;
    const int blockN = blockIdx.x * 64;
    const int blockM = blockIdx.y * 64;

    const int chKey = (tid & 15) ^ ((tid >> 4) & 15);
    const size_t aBase = (size_t)(blockM + (tid >> 4)) * K + chKey * 8;
    const size_t bBase = (size_t)(blockN + (tid >> 4)) * K + chKey * 8;

    f32x4 acc[2][2];
#pragma unroll
    for (int mt = 0; mt < 2; ++mt)
#pragma unroll
        for (int nt = 0; nt < 2; ++nt) { f32x4 z = {0.f, 0.f, 0.f, 0.f}; acc[mt][nt] = z; }

    for (int k0 = 0; k0 < K; k0 += 128) {
#pragma unroll
        for (int j = 0; j < 4; ++j) {
            gload_lds16(A  + aBase + (size_t)j * 16 * K + k0, sA + j * 2048 + wid * 512);
            gload_lds16(Bw + bBase + (size_t)j * 16 * K + k0, sB + j * 2048 + wid * 512);
        }
        __syncthreads();
#pragma unroll
        for (int ks = 0; ks < 4; ++ks) {
            const int ch = ((ks << 2) + q) ^ r;
            bf16x8 af[2], bf[2];
#pragma unroll
            for (int mt = 0; mt < 2; ++mt) af[mt] = *(const bf16x8*)&sA[(wr * 32 + mt * 16 + r) * 128 + ch * 8];
#pragma unroll
            for (int nt = 0; nt < 2; ++nt) bf[nt] = *(const bf16x8*)&sB[(wc * 32 + nt * 16 + r) * 128 + ch * 8];
#pragma unroll
            for (int mt = 0; mt < 2; ++mt)
#pragma unroll
                for (int nt = 0; nt < 2; ++nt)
                    acc[mt][nt] = __builtin_amdgcn_mfma_f32_16x16x32_bf16(af[mt], bf[nt], acc[mt][nt], 0, 0, 0);
        }
        __syncthreads();
    }

#pragma unroll
    for (int mt = 0; mt < 2; ++mt) {
        const int row0 = blockM + wr * 32 + mt * 16 + q * 4;
#pragma unroll
        for (int nt = 0; nt < 2; ++nt) {
            const int col = blockN + wc * 32 + nt * 16 + r;
#pragma unroll
            for (int reg = 0; reg < 4; ++reg)
                W[(size_t)(row0 + reg) * DIN + col] = f2bf(acc[mt][nt][reg]);
        }
    }
}

// ---------------------------------------------------------------------------
// gemmS r20: persistent, BM=256 x BN=128, 8 waves (4M x 2N), acc[4][4],
// frag dbuf (sets E/O). 128 phases (slot = K=32 unit; 16 slots/N-tile).
// Slot u -> LDS region u&3 (buf=(u>>1)&1, kh=u&1). Phase s: RD slot s into
// set s&1; STG slot s+3; MM slot s-1 from set (s-1)&1; VMC(6); LGKM0; BAR.
// LDS (shorts): A units buf*16384+kh*8192 [0,32768); B units 32768+buf*8192
// +kh*4096; bias f32 at 49152. 100 KB. Swizzle: chunk c holds global chunk
// c ^ ((row>>1)&3) (pre-swizzled source, linear dest); frag chunk q^((r>>1)&3).
// ---------------------------------------------------------------------------
__global__ __launch_bounds__(512, 2) void gemmS_kernel(
    const unsigned short* __restrict__ A,   // xb bf16 [BATCH, DIN]
    const unsigned short* __restrict__ Bw,  // W bf16 [DOUT, DIN]
    const float* __restrict__ bp,           // b' [DOUT]
    float* __restrict__ partials) {         // [BATCH, 4]
    constexpr int K = DIN;                   // 512
    __shared__ __align__(16) unsigned short lds[51200];  // 100 KB

    const int tid  = threadIdx.x;            // 0..511
    const int lane = tid & 63;
    const int wid  = tid >> 6;               // 0..7
    const int wr   = wid >> 1;               // 0..3 (M)
    const int wc   = wid & 1;                // 0..1 (N)
    const int r    = lane & 15, q = lane >> 4;

    // 256 blocks = 8 xcd x 32. mIdx = xcd*16 + (j>>1), nHalf = j&1.
    const int b     = blockIdx.x;
    const int xcd   = b & 7;
    const int j     = b >> 3;
    const int nHalf = j & 1;
    const int blockM = (xcd * 16 + (j >> 1)) * 256;
    const int nBase  = nHalf * 1024;         // walks 8 N-tiles of 128 cols

    // staging addresses (pre-swizzled global source)
    const int sRow = tid >> 2;
    const int swz  = (tid & 3) ^ ((tid >> 3) & 3);
    const unsigned short* aSrc = A  + (size_t)(blockM + sRow) * K + swz * 8;
    const unsigned short* bCur = Bw + (size_t)(nBase  + sRow) * K + swz * 8;
    float* biasLds = (float*)(lds + 49152);

#define STAGE_A(ptr, buf, kh, kt) do {                                          \
    gload_lds16((ptr) + (kt) * 64 + (kh) * 32,                                  \
                lds + (buf) * 16384 + (kh) * 8192 + wid * 512);                 \
    gload_lds16((ptr) + 128 * K + (kt) * 64 + (kh) * 32,                        \
                lds + (buf) * 16384 + (kh) * 8192 + 4096 + wid * 512);          \
} while (0)
#define STAGE_B(ptr, buf, kh, kt) do {                                          \
    gload_lds16((ptr) + (kt) * 64 + (kh) * 32,                                  \
                lds + 32768 + (buf) * 8192 + (kh) * 4096 + wid * 512);          \
} while (0)

    // fragment read bases (swizzled chunk)
    const int rsw  = (r >> 1) & 3;
    const int fOff = (q ^ rsw) * 8;
    const unsigned short* ldsAf = lds + (wr * 64 + r) * 32 + fOff;
    const unsigned short* ldsBf = lds + 32768 + (wc * 64 + r) * 32 + fOff;

    f32x4 acc[4][4];
#pragma unroll
    for (int mt = 0; mt < 4; ++mt)
#pragma unroll
        for (int nt = 0; nt < 4; ++nt) { f32x4 z = {0.f, 0.f, 0.f, 0.f}; acc[mt][nt] = z; }
    float mx[4][4];
#pragma unroll
    for (int mt = 0; mt < 4; ++mt)
#pragma unroll
        for (int rg = 0; rg < 4; ++rg) mx[mt][rg] = -INFINITY;
    bf16x8 afE[4], bfrE[4], afO[4], bfrO[4];
    float bvc[4];

#define RD_E(rb, rk) do {                                                       \
    const unsigned short* pa_ = ldsAf + (rb) * 16384 + (rk) * 8192;             \
    afE[0] = *(const bf16x8*)(pa_);                                             \
    afE[1] = *(const bf16x8*)(pa_ + 512);                                       \
    afE[2] = *(const bf16x8*)(pa_ + 1024);                                      \
    afE[3] = *(const bf16x8*)(pa_ + 1536);                                      \
    const unsigned short* pb_ = ldsBf + (rb) * 8192 + (rk) * 4096;              \
    bfrE[0] = *(const bf16x8*)(pb_);                                            \
    bfrE[1] = *(const bf16x8*)(pb_ + 512);                                      \
    bfrE[2] = *(const bf16x8*)(pb_ + 1024);                                     \
    bfrE[3] = *(const bf16x8*)(pb_ + 1536);                                     \
} while (0)
#define RD_O(rb, rk) do {                                                       \
    const unsigned short* pa_ = ldsAf + (rb) * 16384 + (rk) * 8192;             \
    afO[0] = *(const bf16x8*)(pa_);                                             \
    afO[1] = *(const bf16x8*)(pa_ + 512);                                       \
    afO[2] = *(const bf16x8*)(pa_ + 1024);                                      \
    afO[3] = *(const bf16x8*)(pa_ + 1536);                                      \
    const unsigned short* pb_ = ldsBf + (rb) * 8192 + (rk) * 4096;              \
    bfrO[0] = *(const bf16x8*)(pb_);                                            \
    bfrO[1] = *(const bf16x8*)(pb_ + 512);                                      \
    bfrO[2] = *(const bf16x8*)(pb_ + 1024);                                     \
    bfrO[3] = *(const bf16x8*)(pb_ + 1536);                                     \
} while (0)
#define MM_E() do {                                                             \
    __builtin_amdgcn_s_setprio(1);                                              \
    _Pragma("unroll") for (int m_ = 0; m_ < 4; ++m_)                            \
    _Pragma("unroll") for (int n_ = 0; n_ < 4; ++n_)                            \
        acc[m_][n_] = __builtin_amdgcn_mfma_f32_16x16x32_bf16(                  \
            afE[m_], bfrE[n_], acc[m_][n_], 0, 0, 0);                           \
    __builtin_amdgcn_s_setprio(0);                                              \
} while (0)
#define MM_O() do {                                                             \
    __builtin_amdgcn_s_setprio(1);                                              \
    _Pragma("unroll") for (int m_ = 0; m_ < 4; ++m_)                            \
    _Pragma("unroll") for (int n_ = 0; n_ < 4; ++n_)                            \
        acc[m_][n_] = __builtin_amdgcn_mfma_f32_16x16x32_bf16(                  \
            afO[m_], bfrO[n_], acc[m_][n_], 0, 0, 0);                           \
    __builtin_amdgcn_s_setprio(0);                                              \
} while (0)
#define BARS()  do { __builtin_amdgcn_s_barrier();                              \
                     __builtin_amdgcn_sched_barrier(0); } while (0)
#define LGKM0() asm volatile("s_waitcnt lgkmcnt(0)" ::: "memory")
#define VMC(n)  asm volatile("s_waitcnt vmcnt(" #n ")" ::: "memory")

#define FOLD() do {                                                             \
    _Pragma("unroll") for (int mt_ = 0; mt_ < 4; ++mt_)                         \
    _Pragma("unroll") for (int rg_ = 0; rg_ < 4; ++rg_) {                       \
        float v_ = fmaxf(fmaxf(acc[mt_][0][rg_] + bvc[0],                       \
                               acc[mt_][1][rg_] + bvc[1]),                      \
                         fmaxf(acc[mt_][2][rg_] + bvc[2],                       \
                               acc[mt_][3][rg_] + bvc[3]));                     \
        mx[mt_][rg_] = fmaxf(mx[mt_][rg_], v_);                                 \
    }                                                                           \
} while (0)
#define ACC_ZERO() do {                                                         \
    _Pragma("unroll") for (int mt_ = 0; mt_ < 4; ++mt_)                         \
    _Pragma("unroll") for (int nt_ = 0; nt_ < 4; ++nt_) {                       \
        f32x4 z_ = {0.f, 0.f, 0.f, 0.f}; acc[mt_][nt_] = z_;                    \
    }                                                                           \
} while (0)

// Phase s: RD slot s (set RS, region rb/rk) | STG slot s+3 (sb/sk/st from BP)
// | MM slot s-1 (set MS) | VMC(6) forces slot s+1 | LGKM0 drains this
// phase's reads (WAR guard) | BAR publishes slot s+1.
#define PH(RS, rb, rk, MS, BP, sb, sk, st)  do {                                \
    RD_##RS(rb, rk);                                                            \
    STAGE_A(aSrc, sb, sk, st); STAGE_B(BP, sb, sk, st);                         \
    MM_##MS();                                                                  \
    VMC(6); LGKM0(); BARS();                                                    \
} while (0)

// phases 1..12 of a tile (stages stay within tile; slots s+3 = 4..15)
#define PHASES_1_12(BP)                                                         \
    PH(O, 0, 1, E, BP, 0, 0, 2);                                                \
    PH(E, 1, 0, O, BP, 0, 1, 2);                                                \
    PH(O, 1, 1, E, BP, 1, 0, 3);                                                \
    PH(E, 0, 0, O, BP, 1, 1, 3);                                                \
    PH(O, 0, 1, E, BP, 0, 0, 4);                                                \
    PH(E, 1, 0, O, BP, 0, 1, 4);                                                \
    PH(O, 1, 1, E, BP, 1, 0, 5);                                                \
    PH(E, 0, 0, O, BP, 1, 1, 5);                                                \
    PH(O, 0, 1, E, BP, 0, 0, 6);                                                \
    PH(E, 1, 0, O, BP, 0, 1, 6);                                                \
    PH(O, 1, 1, E, BP, 1, 0, 7);                                                \
    PH(E, 0, 0, O, BP, 1, 1, 7);

// phases 13..15 (stages roll into next tile's slots 0..2)
#define PHASES_13_15(BPN)                                                       \
    PH(O, 0, 1, E, BPN, 0, 0, 0);                                               \
    PH(E, 1, 0, O, BPN, 0, 1, 0);                                               \
    PH(O, 1, 1, E, BPN, 1, 0, 1);

    // Bias -> LDS (own ds_write drained before barrier).
    {
        float2 bb = ((const float2*)(bp + nBase))[tid];
        ((float2*)biasLds)[tid] = bb;
    }
    LGKM0();

    // Prologue: stage slots 0,1,2 (9 loads); VMC(3) lands slots 0,1.
    STAGE_A(aSrc, 0, 0, 0); STAGE_B(bCur, 0, 0, 0);   // slot0
    STAGE_A(aSrc, 0, 1, 0); STAGE_B(bCur, 0, 1, 0);   // slot1
    STAGE_A(aSrc, 1, 0, 1); STAGE_B(bCur, 1, 0, 1);   // slot2
    VMC(3);
    BARS();

    // bias for N-tile 0
#pragma unroll
    for (int nt = 0; nt < 4; ++nt) bvc[nt] = biasLds[wc * 64 + nt * 16 + r];

    // ---- tile 0, phase 0 (no MM) ----
    RD_E(0, 0);
    STAGE_A(aSrc, 1, 1, 1); STAGE_B(bCur, 1, 1, 1);   // slot3
    VMC(6); LGKM0(); BARS();
    // ---- tile 0, phases 1..15 ----
    PHASES_1_12(bCur);
    {
        const unsigned short* bNxt = bCur + 128 * K;
        PHASES_13_15(bNxt);
        bCur = bNxt;
    }

    // ---- tiles 1..6 ----
    int bOff = 128;   // bias offset of current tile
#pragma unroll 1
    for (int t = 1; t < 7; ++t) {
        // phase 0: MM finishes prev tile's last slot -> fold
        RD_E(0, 0);
        STAGE_A(aSrc, 1, 1, 1); STAGE_B(bCur, 1, 1, 1);
        MM_O();
        FOLD(); ACC_ZERO();
#pragma unroll
        for (int nt = 0; nt < 4; ++nt) bvc[nt] = biasLds[bOff + wc * 64 + nt * 16 + r];
        VMC(6); LGKM0(); BARS();
        PHASES_1_12(bCur);
        const unsigned short* bNxt = bCur + 128 * K;
        PHASES_13_15(bNxt);
        bCur = bNxt;
        bOff += 128;
    }

    // ---- tile 7 ----
    RD_E(0, 0);
    STAGE_A(aSrc, 1, 1, 1); STAGE_B(bCur, 1, 1, 1);
    MM_O();
    FOLD(); ACC_ZERO();
#pragma unroll
    for (int nt = 0; nt < 4; ++nt) bvc[nt] = biasLds[896 + wc * 64 + nt * 16 + r];
    VMC(6); LGKM0(); BARS();
    PHASES_1_12(bCur);
    // drain phases 13..15 (no stages left)
    RD_O(0, 1); MM_E(); VMC(3); LGKM0(); BARS();
    RD_E(1, 0); MM_O(); VMC(0); LGKM0(); BARS();
    RD_O(1, 1); MM_E(); LGKM0();
    // tail: MM of slot 127
    MM_O();
    FOLD();

#undef STAGE_A
#undef STAGE_B
#undef RD_E
#undef RD_O
#undef MM_E
#undef MM_O
#undef BARS
#undef LGKM0
#undef VMC
#undef FOLD
#undef ACC_ZERO
#undef PH
#undef PHASES_1_12
#undef PHASES_13_15

    // Final epilogue (once): 16-lane reduce of mx, store partials [BATCH,4].
#pragma unroll
    for (int mt = 0; mt < 4; ++mt) {
#pragma unroll
        for (int rg = 0; rg < 4; ++rg) {
            float v = mx[mt][rg];
#pragma unroll
            for (int off = 1; off < 16; off <<= 1)
                v = fmaxf(v, __shfl_xor(v, off));
            if (r == 0) {
                const int row = blockM + wr * 64 + mt * 16 + q * 4 + rg;
                partials[(size_t)row * 4 + nHalf * 2 + wc] = v;
            }
        }
    }
}

// ---------------------------------------------------------------------------
// reduce: 4 partials per row -> final max
// ---------------------------------------------------------------------------
__global__ __launch_bounds__(256) void reduce_kernel(
    const float4* __restrict__ partials, float* __restrict__ out) {
    const int row = blockIdx.x * blockDim.x + threadIdx.x;
    float4 v = partials[row];
    out[row] = fmaxf(fmaxf(v.x, v.y), fmaxf(v.z, v.w));
}

// ---------------------------------------------------------------------------
extern "C" void kernel_launch(void* const* d_in, const int* in_sizes, int n_in,
                              void* d_out, int out_size, void* d_ws, size_t ws_size,
                              hipStream_t stream) {
    const float* x   = (const float*)d_in[0];
    const float* l1w = (const float*)d_in[1];
    const float* l1b = (const float*)d_in[2];
    const float* w2  = (const float*)d_in[3];
    const float* b2  = (const float*)d_in[4];
    float* out = (float*)d_out;

    char* ws = (char*)d_ws;
    unsigned short* w1t = (unsigned short*)(ws);                 //  1 MB  w1^T bf16 [512,1024]
    unsigned short* w2b = (unsigned short*)(ws + 1048576);       //  4 MB  w2 bf16 [2048,1024]
    unsigned short* Wb  = (unsigned short*)(ws + 5242880);       //  2 MB  W bf16 [2048,512]
    float* bp           = (float*)(ws + 7340032);                //  8 KB  b' fp32 [2048]
    unsigned short* xb  = (unsigned short*)(ws + 7348224);       // 32 MB  x bf16 [32768,512]
    float* partials     = (float*)(ws + 40902656);               // 512 KB [BATCH,4]

    // 1) fused pre-work: w1 transpose + w2 cvt(+bgemv) + x cvt
    prep_kernel<<<6656, 256, 0, stream>>>(
        l1w, (const float4*)w2, (const float4*)x, l1b, b2,
        w1t, (ushort4*)w2b, (ushort4*)xb, bp);

    // 2) W = w2b @ w1t^T  [2048, 512]
    gemmW_kernel<<<dim3(DIN / 64, DOUT / 64), 256, 0, stream>>>(w2b, w1t, Wb);

    // 3) scores = xb @ W^T + b', fused row-max (persistent, 256 blocks)
    gemmS_kernel<<<256, 512, 0, stream>>>(xb, Wb, bp, partials);

    // 4) final max over 4 partials per row
    reduce_kernel<<<BATCH / 256, 256, 0, stream>>>((const float4*)partials, out);
}